// Round 5
// baseline (985.352 us; speedup 1.0000x reference)
//
#include <hip/hip_runtime.h>
#include <math.h>

#define NEGINF (-INFINITY)
constexpr int Np = 4096;
constexpr int Kn = 20;
constexpr float EPSf = 1e-5f;
constexpr float SLOPE = 0.2f;

typedef __bf16 bf16x8 __attribute__((ext_vector_type(8)));
typedef float f32x4 __attribute__((ext_vector_type(4)));
typedef unsigned long long ull;
typedef unsigned int u32;

// ---------------- K1: knn1 (lane-private rows) + edgeconv1 ----------------
// grid (64, B), 64 threads (1 wave). Lane owns point n = n0 + L.
// Phase 1: scan all 4096 points, s = |xi-xj|^2, key = (~bits(s)<<32)|~j (desc).
// Phase 2: wave processes its 64 points, lane = output channel.
__global__ __launch_bounds__(64) void k1_knn1_edge1(
    const float* __restrict__ x, const float* __restrict__ W1,
    const float* __restrict__ g1, const float* __restrict__ b1,
    const float* __restrict__ m1, const float* __restrict__ v1,
    float* __restrict__ x1, __bf16* __restrict__ x1h, __bf16* __restrict__ x1l,
    float* __restrict__ xx2)
{
  __shared__ float2 sxy[Np];          // 32 KB (phase-2 random access)
  __shared__ ull    pbuf[20][64];     // 10 KB slot-major push stacks
  __shared__ u32    stopidx[64][20];  // 5 KB

  const int b = blockIdx.y;
  const int n0 = blockIdx.x * 64;
  const int L = threadIdx.x;
  const float* __restrict__ xr = x + (size_t)b*2*Np;
  const float* __restrict__ yr = xr + Np;

  // stage coords for phase 2 (single wave, no barrier needed)
  for (int j = L*8; j < Np; j += 512) {
    float4 xv = *reinterpret_cast<const float4*>(xr + j);
    float4 xv2 = *reinterpret_cast<const float4*>(xr + j + 4);
    float4 yv = *reinterpret_cast<const float4*>(yr + j);
    float4 yv2 = *reinterpret_cast<const float4*>(yr + j + 4);
    sxy[j+0] = make_float2(xv.x, yv.x);  sxy[j+1] = make_float2(xv.y, yv.y);
    sxy[j+2] = make_float2(xv.z, yv.z);  sxy[j+3] = make_float2(xv.w, yv.w);
    sxy[j+4] = make_float2(xv2.x, yv2.x); sxy[j+5] = make_float2(xv2.y, yv2.y);
    sxy[j+6] = make_float2(xv2.z, yv2.z); sxy[j+7] = make_float2(xv2.w, yv2.w);
  }

  const int n = n0 + L;
  const float px = xr[n], py = yr[n];

  ull kv[20];
#pragma unroll
  for (int s = 0; s < 20; ++s) kv[s] = 0ull;
  float s_cut = INFINITY;
  int cnt = 0;

  auto flushK = [&]() {
#pragma unroll 1
    for (int f = 0; f < 20; ++f) {
      if (__all(f >= cnt)) break;
      ull key = pbuf[f][L];
      if (f < cnt && key > kv[19]) {
        ull ck = key;
#pragma unroll
        for (int s = 0; s < 20; ++s) {
          bool sw = ck > kv[s];
          ull tv = kv[s];
          kv[s] = sw ? ck : kv[s];
          ck = sw ? tv : ck;
        }
      }
    }
    cnt = 0;
    u32 hk = (u32)(kv[19] >> 32);
    if (hk) s_cut = __uint_as_float(~hk);   // kv full -> tighten filter
  };

  // phase 1: scan (coord loads are wave-uniform -> scalar path)
  for (int j0 = 0; j0 < Np; j0 += 16) {
#pragma unroll
    for (int c = 0; c < 4; ++c) {
      float4 xv = *reinterpret_cast<const float4*>(xr + j0 + c*4);
      float4 yv = *reinterpret_cast<const float4*>(yr + j0 + c*4);
      const float xs[4] = {xv.x, xv.y, xv.z, xv.w};
      const float ys[4] = {yv.x, yv.y, yv.z, yv.w};
#pragma unroll
      for (int r = 0; r < 4; ++r) {
        float dx = xs[r] - px, dy = ys[r] - py;
        float s = dx*dx + dy*dy;
        if (s <= s_cut) {
          int j = j0 + c*4 + r;
          pbuf[cnt][L] = (((ull)~__float_as_uint(s)) << 32) | (u32)~(u32)j;
          ++cnt;
        }
      }
    }
    if (__any(cnt >= 4)) flushK();
  }
  flushK();

#pragma unroll
  for (int k = 0; k < Kn; ++k) stopidx[L][k] = ~(u32)kv[k];

  // phase 2: edgeconv1, lane = channel o, loop over the wave's 64 points
  const int o = L;
  const float4 w1v = reinterpret_cast<const float4*>(W1)[o];
  const float sc = g1[o] / sqrtf(v1[o] + EPSf);
  const float mo = m1[o], bo = b1[o];

  for (int p = 0; p < 64; ++p) {
    const int np = n0 + p;
    float2 cp = sxy[np];
    const float cx0 = cp.x, cx1 = cp.y;
    const float cterm = w1v.z*cx0 + w1v.w*cx1 - w1v.x*cx0 - w1v.y*cx1;
    float xm = NEGINF;
#pragma unroll
    for (int k = 0; k < Kn; ++k) {
      int j = stopidx[p][k];
      float2 pj = sxy[j];
      float vv = w1v.x*pj.x + w1v.y*pj.y + cterm;
      float h = (vv - mo)*sc + bo;
      h = h >= 0.f ? h : SLOPE*h;
      xm = fmaxf(xm, h);
    }
    x1[(b*64 + o)*Np + np] = xm;
    __bf16 hb = (__bf16)xm;
    __bf16 lb = (__bf16)(xm - (float)hb);
    size_t tbase = ((size_t)b*Np + np)*64 + o;
    x1h[tbase] = hb;
    x1l[tbase] = lb;
    float s = xm*xm;
#pragma unroll
    for (int off = 1; off < 64; off <<= 1) s += __shfl_xor(s, off);
    if (L == 0) xx2[b*Np + np] = s;
  }
}

// ---------------- K2: knn2 — swapped-operand MFMA gram, 2-way column split ----------------
// grid (256 rowblocks, 2 halves, B), 64 threads. Block: 16 rows x 2048 cols.
// D[n=L15 -> row][m=quad*4+r -> col]; lane owns one row; per-half top-20 -> cand.
__global__ __launch_bounds__(64) void k2_knn2(
    const __bf16* __restrict__ xh, const __bf16* __restrict__ xl,
    const float* __restrict__ xx2, ull* __restrict__ cand)
{
  __shared__ float sxxl[2048];        // 8 KB: this half's norms
  __shared__ ull   pool[1344];        // 10.5 KB: pbuf[12][64] then skv[64][21]

  const int b = blockIdx.z;
  const int half = blockIdx.y;
  const int n0 = blockIdx.x * 16;
  const int L = threadIdx.x;
  const int L15 = L & 15, quad = L >> 4;

  for (int j = L*4; j < 2048; j += 256)
    *reinterpret_cast<float4*>(&sxxl[j]) =
      *reinterpret_cast<const float4*>(&xx2[(size_t)b*Np + half*2048 + j]);

  // B operand: rows n0..n0+15 (loaded once)
  const __bf16* Rh = xh + ((size_t)b*Np + n0)*64;
  const __bf16* Rl = xl + ((size_t)b*Np + n0)*64;
  bf16x8 rh0 = *reinterpret_cast<const bf16x8*>(Rh + L15*64 +  0 + quad*8);
  bf16x8 rh1 = *reinterpret_cast<const bf16x8*>(Rh + L15*64 + 32 + quad*8);
  bf16x8 rl0 = *reinterpret_cast<const bf16x8*>(Rl + L15*64 +  0 + quad*8);
  bf16x8 rl1 = *reinterpret_cast<const bf16x8*>(Rl + L15*64 + 32 + quad*8);

  const __bf16* Cbh = xh + ((size_t)b*Np + half*2048)*64;
  const __bf16* Cbl = xl + ((size_t)b*Np + half*2048)*64;

  ull kv[20];
#pragma unroll
  for (int s = 0; s < 20; ++s) kv[s] = 0ull;
  ull thresh = 0ull;
  float fthresh = NEGINF;
  int cnt = 0;

  auto flush = [&]() {
#pragma unroll 1
    for (int f = 0; f < 12; ++f) {
      if (__all(f >= cnt)) break;
      ull key = pool[f*64 + L];
      if (f < cnt && key > kv[19]) {
        ull ck = key;
#pragma unroll
        for (int s = 0; s < 20; ++s) {
          bool sw = ck > kv[s];
          ull tv = kv[s];
          kv[s] = sw ? ck : kv[s];
          ck = sw ? tv : ck;
        }
      }
    }
    cnt = 0;
    // row threshold = max over the row's 4 quad-lanes (exact lower bound)
    ull t = kv[19];
    ull t2 = __shfl_xor(t, 16); t = t2 > t ? t2 : t;
    t2 = __shfl_xor(t, 32);     t = t2 > t ? t2 : t;
    thresh = t;
    if (thresh != 0ull) {
      u32 hk = (u32)(thresh >> 32);
      u32 u = hk ^ ((hk >> 31) ? 0x80000000u : 0xFFFFFFFFu);
      fthresh = __uint_as_float(u);
    }
  };

  for (int tt = 0; tt < 32; ++tt) {
    // A fragments: 4 sub-tiles of 16 cols (scattered 16B loads, L2-resident)
    const __bf16* ph = Cbh + (size_t)(tt*64)*64;
    const __bf16* pl = Cbl + (size_t)(tt*64)*64;
    bf16x8 AH[4][2], AL[4][2];
#pragma unroll
    for (int s = 0; s < 4; ++s) {
      AH[s][0] = *reinterpret_cast<const bf16x8*>(ph + (s*16 + L15)*64 +  0 + quad*8);
      AH[s][1] = *reinterpret_cast<const bf16x8*>(ph + (s*16 + L15)*64 + 32 + quad*8);
      AL[s][0] = *reinterpret_cast<const bf16x8*>(pl + (s*16 + L15)*64 +  0 + quad*8);
      AL[s][1] = *reinterpret_cast<const bf16x8*>(pl + (s*16 + L15)*64 + 32 + quad*8);
    }

    f32x4 acc[4];
#pragma unroll
    for (int s = 0; s < 4; ++s) {
      acc[s] = (f32x4){0.f, 0.f, 0.f, 0.f};
      acc[s] = __builtin_amdgcn_mfma_f32_16x16x32_bf16(AH[s][0], rh0, acc[s], 0, 0, 0);
      acc[s] = __builtin_amdgcn_mfma_f32_16x16x32_bf16(AH[s][1], rh1, acc[s], 0, 0, 0);
      acc[s] = __builtin_amdgcn_mfma_f32_16x16x32_bf16(AH[s][0], rl0, acc[s], 0, 0, 0);
      acc[s] = __builtin_amdgcn_mfma_f32_16x16x32_bf16(AH[s][1], rl1, acc[s], 0, 0, 0);
      acc[s] = __builtin_amdgcn_mfma_f32_16x16x32_bf16(AL[s][0], rh0, acc[s], 0, 0, 0);
      acc[s] = __builtin_amdgcn_mfma_f32_16x16x32_bf16(AL[s][1], rh1, acc[s], 0, 0, 0);
    }

#pragma unroll
    for (int s = 0; s < 4; ++s) {
      float4 xv = *reinterpret_cast<const float4*>(&sxxl[tt*64 + s*16 + quad*4]);
      const float xvr[4] = {xv.x, xv.y, xv.z, xv.w};
#pragma unroll
      for (int r = 0; r < 4; ++r) {
        float e = 2.0f*acc[s][r] - xvr[r];
        if (e >= fthresh) {
          int j = half*2048 + tt*64 + s*16 + quad*4 + r;
          u32 u = __float_as_uint(e);
          u32 hk = u ^ ((u32)((int)u >> 31) | 0x80000000u);
          pool[cnt*64 + L] = (((ull)hk) << 32) | (u32)~(u32)j;
          ++cnt;
        }
      }
      if ((s & 1) && __any(cnt >= 4)) flush();   // cap 12: max cnt 3+8=11
    }
  }
  flush();

  // dump lane lists into pool (pbuf dead), merge 4 quads per row -> cand
#pragma unroll
  for (int k = 0; k < Kn; ++k) pool[L*21 + k] = kv[k];
  if (L < 16) {
    const int r = L;
    int p0 = 0, p1 = 0, p2 = 0, p3 = 0;
    size_t obase = (((size_t)b*Np + n0 + r)*2 + half)*Kn;
    for (int k = 0; k < Kn; ++k) {
      ull v0 = (p0 < 20) ? pool[( 0 + r)*21 + p0] : 0ull;
      ull v1 = (p1 < 20) ? pool[(16 + r)*21 + p1] : 0ull;
      ull v2 = (p2 < 20) ? pool[(32 + r)*21 + p2] : 0ull;
      ull v3 = (p3 < 20) ? pool[(48 + r)*21 + p3] : 0ull;
      ull best = v0; int sel = 0;
      if (v1 > best) { best = v1; sel = 1; }
      if (v2 > best) { best = v2; sel = 2; }
      if (v3 > best) { best = v3; sel = 3; }
      cand[obase + k] = best;
      p0 += (sel == 0); p1 += (sel == 1); p2 += (sel == 2); p3 += (sel == 3);
    }
  }
}

// ---------------- K2c: merge the two half-lists per row -> idx2 ----------------
__global__ __launch_bounds__(256) void k2c_merge(
    const ull* __restrict__ cand, int* __restrict__ idx2)
{
  const int row = blockIdx.x*256 + threadIdx.x;   // b*Np + n
  const ull* A = cand + (size_t)row*2*Kn;
  const ull* B = A + Kn;
  int pa = 0, pb = 0;
  for (int k = 0; k < Kn; ++k) {
    ull va = (pa < Kn) ? A[pa] : 0ull;
    ull vb = (pb < Kn) ? B[pb] : 0ull;
    bool tb = vb > va;
    idx2[(size_t)row*Kn + k] = (int)~(u32)(tb ? vb : va);
    pa += !tb; pb += tb;
  }
}

// ---------------- K3: edgeconv2 (one wave per point, W2 rows in registers) ----------------
__global__ __launch_bounds__(256) void k3_edge2(
    const __bf16* __restrict__ xh, const __bf16* __restrict__ xl,
    const int* __restrict__ idx2,
    const float* __restrict__ W2,
    const float* __restrict__ g2, const float* __restrict__ b2,
    const float* __restrict__ m2, const float* __restrict__ v2,
    float* __restrict__ x2)
{
  __shared__ float scen[4][64];
  __shared__ float snbr[4][64];
  const int b = blockIdx.y;
  const int tid = threadIdx.x;
  const int w = tid >> 6, L = tid & 63;
  const int n = blockIdx.x*4 + w;

  float4 w2a[16], w2b[16];
#pragma unroll
  for (int q = 0; q < 16; ++q) {
    w2a[q] = reinterpret_cast<const float4*>(W2 + L*128)[q];
    w2b[q] = reinterpret_cast<const float4*>(W2 + L*128 + 64)[q];
  }
  const float sc2 = g2[L]/sqrtf(v2[L]+EPSf);
  const float m2o = m2[L], b2o = b2[L];

  float cen = (float)xh[((size_t)b*Np + n)*64 + L] + (float)xl[((size_t)b*Np + n)*64 + L];
  scen[w][L] = cen;
  __syncthreads();
  float u = 0.f, t2 = 0.f;
#pragma unroll
  for (int q = 0; q < 16; ++q) {
    float4 cv = *reinterpret_cast<const float4*>(&scen[w][q*4]);
    u  += w2a[q].x*cv.x + w2a[q].y*cv.y + w2a[q].z*cv.z + w2a[q].w*cv.w;
    t2 += w2b[q].x*cv.x + w2b[q].y*cv.y + w2b[q].z*cv.z + w2b[q].w*cv.w;
  }

  const int* ip = idx2 + ((size_t)b*Np + n)*Kn;
  float xm = NEGINF;
  int j0 = ip[0];
  float cur = (float)xh[((size_t)b*Np + j0)*64 + L] + (float)xl[((size_t)b*Np + j0)*64 + L];
  for (int k = 0; k < Kn; ++k) {
    float nxt = 0.f;
    if (k+1 < Kn) {
      int jn = ip[k+1];
      nxt = (float)xh[((size_t)b*Np + jn)*64 + L] + (float)xl[((size_t)b*Np + jn)*64 + L];
    }
    snbr[w][L] = cur;
    float a = 0.f;
#pragma unroll
    for (int q = 0; q < 16; ++q) {
      float4 nv = *reinterpret_cast<const float4*>(&snbr[w][q*4]);
      a += w2a[q].x*nv.x + w2a[q].y*nv.y + w2a[q].z*nv.z + w2a[q].w*nv.w;
    }
    float vv = a - u + t2;
    float hh = (vv - m2o)*sc2 + b2o;
    hh = hh >= 0.f ? hh : SLOPE*hh;
    xm = fmaxf(xm, hh);
    cur = nxt;
  }
  x2[(b*64 + L)*Np + n] = xm;
}

// ---------------- K4: conv5 + per-block max over n ----------------
__global__ __launch_bounds__(256) void k4_conv5max(
    const float* __restrict__ x1, const float* __restrict__ x2,
    const float* __restrict__ W5,
    const float* __restrict__ g5, const float* __restrict__ b5,
    const float* __restrict__ m5, const float* __restrict__ v5,
    float* __restrict__ partials)  // (B,128,64)
{
  const int b = blockIdx.y, nb = blockIdx.x;
  const int tid = threadIdx.x;
  const int p = tid & 63;
  const int g = __builtin_amdgcn_readfirstlane(tid >> 6);
  const int n = nb*64 + p;
  float xcr[128];
#pragma unroll
  for (int c = 0; c < 64; ++c) {
    xcr[c]    = x1[(b*64 + c)*Np + n];
    xcr[64+c] = x2[(b*64 + c)*Np + n];
  }
  for (int oi = 0; oi < 32; ++oi) {
    const int o = g*32 + oi;
    const float* wr = W5 + o*128;
    float dot = 0.f;
#pragma unroll
    for (int c = 0; c < 128; c += 4) {
      float4 wv = *reinterpret_cast<const float4*>(wr + c);
      dot += wv.x*xcr[c] + wv.y*xcr[c+1] + wv.z*xcr[c+2] + wv.w*xcr[c+3];
    }
    float hv = (dot - m5[o])*(g5[o]/sqrtf(v5[o]+EPSf)) + b5[o];
    hv = hv >= 0.f ? hv : SLOPE*hv;
#pragma unroll
    for (int off = 1; off < 64; off <<= 1) hv = fmaxf(hv, __shfl_xor(hv, off));
    if (p == 0) partials[(b*128 + o)*64 + nb] = hv;
  }
}

// ---------------- K5: reduce partial maxima -> gmax, then t6 = W6a * gmax ----------------
__global__ __launch_bounds__(256) void k5_reduce_t6(
    const float* __restrict__ partials, const float* __restrict__ W6,
    float* __restrict__ t6)  // (B,256)
{
  __shared__ float sg[128];
  const int b = blockIdx.x;
  const int tid = threadIdx.x;
  if (tid < 128) {
    float m = NEGINF;
    for (int w = 0; w < 64; ++w) m = fmaxf(m, partials[(b*128 + tid)*64 + w]);
    sg[tid] = m;
  }
  __syncthreads();
  float a = 0.f;
#pragma unroll
  for (int c = 0; c < 128; c += 4) {
    float4 wv = *reinterpret_cast<const float4*>(W6 + tid*256 + c);
    a += wv.x*sg[c] + wv.y*sg[c+1] + wv.z*sg[c+2] + wv.w*sg[c+3];
  }
  t6[b*256 + tid] = a;
}

// ---------------- K6: conv6 (W6b part + t6) + bn + lrelu + W9 dot ----------------
__global__ __launch_bounds__(256) void k6_conv6_out(
    const float* __restrict__ x1, const float* __restrict__ x2,
    const float* __restrict__ W6, const float* __restrict__ t6,
    const float* __restrict__ g6, const float* __restrict__ b6,
    const float* __restrict__ m6, const float* __restrict__ v6,
    const float* __restrict__ W9,
    float* __restrict__ out)
{
  __shared__ float red[4][64];
  const int b = blockIdx.y, nb = blockIdx.x;
  const int tid = threadIdx.x;
  const int p = tid & 63;
  const int g = __builtin_amdgcn_readfirstlane(tid >> 6);
  const int n = nb*64 + p;
  float xcr[128];
#pragma unroll
  for (int c = 0; c < 64; ++c) {
    xcr[c]    = x1[(b*64 + c)*Np + n];
    xcr[64+c] = x2[(b*64 + c)*Np + n];
  }
  float oacc = 0.f;
  for (int oi = 0; oi < 64; ++oi) {
    const int o = g*64 + oi;
    const float* wr = W6 + o*256 + 128;
    float dot = t6[b*256 + o];
#pragma unroll
    for (int c = 0; c < 128; c += 4) {
      float4 wv = *reinterpret_cast<const float4*>(wr + c);
      dot += wv.x*xcr[c] + wv.y*xcr[c+1] + wv.z*xcr[c+2] + wv.w*xcr[c+3];
    }
    float hv = (dot - m6[o])*(g6[o]/sqrtf(v6[o]+EPSf)) + b6[o];
    hv = hv >= 0.f ? hv : SLOPE*hv;
    oacc += W9[o]*hv;
  }
  red[g][p] = oacc;
  __syncthreads();
  if (tid < 64)
    out[b*Np + nb*64 + tid] = red[0][tid] + red[1][tid] + red[2][tid] + red[3][tid];
}

extern "C" void kernel_launch(void* const* d_in, const int* in_sizes, int n_in,
                              void* d_out, int out_size, void* d_ws, size_t ws_size,
                              hipStream_t stream) {
  const float* x  = (const float*)d_in[0];
  const float* W1 = (const float*)d_in[1];
  const float* g1 = (const float*)d_in[2];
  const float* b1 = (const float*)d_in[3];
  const float* m1 = (const float*)d_in[4];
  const float* v1 = (const float*)d_in[5];
  const float* W2 = (const float*)d_in[6];
  const float* g2 = (const float*)d_in[7];
  const float* b2 = (const float*)d_in[8];
  const float* m2 = (const float*)d_in[9];
  const float* v2 = (const float*)d_in[10];
  const float* W5 = (const float*)d_in[11];
  const float* g5 = (const float*)d_in[12];
  const float* b5 = (const float*)d_in[13];
  const float* m5 = (const float*)d_in[14];
  const float* v5 = (const float*)d_in[15];
  const float* W6 = (const float*)d_in[16];
  const float* g6 = (const float*)d_in[17];
  const float* b6 = (const float*)d_in[18];
  const float* m6 = (const float*)d_in[19];
  const float* v6 = (const float*)d_in[20];
  const float* W9 = (const float*)d_in[21];
  float* out = (float*)d_out;

  float* F = (float*)d_ws;
  float*  x1    = F;                         // 1048576
  float*  xx2   = F + 1048576;               // 16384
  __bf16* x1h   = (__bf16*)(F + 1064960);    // 524288 float-slots
  __bf16* x1l   = (__bf16*)(F + 1589248);    // 524288
  float*  x2    = F + 2113536;               // 1048576
  int*    idx2  = (int*)(F + 3162112);       // 327680
  float*  t6    = F + 3489792;               // 1024
  float*  parts = F + 3490816;               // 32768 -> end 3523584
  ull*    cand  = (ull*)(F + 3523584);       // 16384*40 ull = 1310720 float-slots

  k1_knn1_edge1<<<dim3(64,4), 64, 0, stream>>>(x, W1, g1, b1, m1, v1, x1, x1h, x1l, xx2);
  k2_knn2<<<dim3(256,2,4), 64, 0, stream>>>(x1h, x1l, xx2, cand);
  k2c_merge<<<64, 256, 0, stream>>>(cand, idx2);
  k3_edge2<<<dim3(1024,4), 256, 0, stream>>>(x1h, x1l, idx2, W2, g2, b2, m2, v2, x2);
  k4_conv5max<<<dim3(64,4), 256, 0, stream>>>(x1, x2, W5, g5, b5, m5, v5, parts);
  k5_reduce_t6<<<4, 256, 0, stream>>>(parts, W6, t6);
  k6_conv6_out<<<dim3(64,4), 256, 0, stream>>>(x1, x2, W6, t6, g6, b6, m6, v6, W9, out);
}

// Round 6
// 756.222 us; speedup vs baseline: 1.3030x; 1.3030x over previous
//
#include <hip/hip_runtime.h>
#include <math.h>

#define NEGINF (-INFINITY)
constexpr int Np = 4096;
constexpr int Kn = 20;
constexpr float EPSf = 1e-5f;
constexpr float SLOPE = 0.2f;

typedef __bf16 bf16x8 __attribute__((ext_vector_type(8)));
typedef float f32x4 __attribute__((ext_vector_type(4)));
typedef unsigned long long ull;
typedef unsigned int u32;

// ---------------- K1a: knn1 — 4-wave blocks, lane-private top-20, batched flush ---------
// grid (64, B), 256 thr. Block owns 64 points (lane L = point n0+L in every wave).
// Wave w scans candidate slice [w*1024, (w+1)*1024). Coords via wave-uniform s_loads.
// Key = (~bits(d2)<<32) | ~j  (desc key order == asc distance, ties -> lower j).
__global__ __launch_bounds__(256) void k1a_knn1(
    const float* __restrict__ x, int* __restrict__ idx1)
{
  __shared__ ull smem[6144];   // 48 KB: pbuf[24][256] in phase 1; dump[4][64][20] in phase 2

  const int b = blockIdx.y;
  const int n0 = blockIdx.x * 64;
  const int tid = threadIdx.x;
  const int w = tid >> 6, L = tid & 63;
  const float* __restrict__ xr = x + (size_t)b*2*Np;
  const float* __restrict__ yr = xr + Np;

  const int n = n0 + L;
  const float px = xr[n], py = yr[n];

  ull kv[20];
#pragma unroll
  for (int s = 0; s < 20; ++s) kv[s] = 0ull;
  u32 u_cut = 0xFFFFFFFFu;     // accept-all until 20 found
  int cnt = 0;

  auto flushK = [&]() {
#pragma unroll 1
    for (int f0 = 0; f0 < 24; f0 += 8) {
      if (__all(f0 >= cnt)) break;
      ull t0[8];
#pragma unroll
      for (int u = 0; u < 8; ++u) t0[u] = smem[(f0+u)*256 + tid];
#pragma unroll
      for (int u = 0; u < 8; ++u) {
        int f = f0 + u;
        ull key = t0[u];
        if (f < cnt && key > kv[19]) {
          ull ck = key;
#pragma unroll
          for (int s = 0; s < 20; ++s) {
            bool sw = ck > kv[s];
            ull tv = kv[s];
            kv[s] = sw ? ck : kv[s];
            ck = sw ? tv : ck;
          }
        }
      }
    }
    cnt = 0;
    u_cut = ~(u32)(kv[19] >> 32);   // kv[19]==0 -> 0xFFFFFFFF -> accept all
  };

  const int base = w * 1024;
  for (int j0 = base; j0 < base + 1024; j0 += 16) {
#pragma unroll
    for (int c = 0; c < 4; ++c) {
      float4 xv = *reinterpret_cast<const float4*>(xr + j0 + c*4);  // uniform -> s_load
      float4 yv = *reinterpret_cast<const float4*>(yr + j0 + c*4);
      const float xs[4] = {xv.x, xv.y, xv.z, xv.w};
      const float ys[4] = {yv.x, yv.y, yv.z, yv.w};
#pragma unroll
      for (int r = 0; r < 4; ++r) {
        float dx = xs[r] - px, dy = ys[r] - py;
        float s = dx*dx + dy*dy;
        u32 ub = __float_as_uint(s);
        if (ub <= u_cut) {
          int j = j0 + c*4 + r;
          smem[cnt*256 + tid] = (((ull)~ub) << 32) | (u32)~(u32)j;
          ++cnt;
        }
      }
    }
    if (__any(cnt >= 8)) flushK();
  }
  flushK();

  __syncthreads();             // pbuf dead everywhere; switch smem to dump layout
#pragma unroll
  for (int k = 0; k < Kn; ++k) smem[((size_t)w*64 + L)*20 + k] = kv[k];
  __syncthreads();

  if (tid < 64) {
    const int p = tid;
    ull h[4]; int pc[4];
#pragma unroll
    for (int q = 0; q < 4; ++q) { h[q] = smem[((size_t)q*64 + p)*20]; pc[q] = 0; }
    size_t obase = ((size_t)b*Np + n0 + p)*Kn;
    for (int k = 0; k < Kn; ++k) {
      ull best = h[0]; int sel = 0;
      if (h[1] > best) { best = h[1]; sel = 1; }
      if (h[2] > best) { best = h[2]; sel = 2; }
      if (h[3] > best) { best = h[3]; sel = 3; }
      idx1[obase + k] = (int)~(u32)best;
      int np_ = ++pc[sel];
      h[sel] = (np_ < 20) ? smem[((size_t)sel*64 + p)*20 + np_] : 0ull;
    }
  }
}

// ---------------- K1c: edgeconv1 — wave per point, lane = channel ----------------
__global__ __launch_bounds__(256) void k1c_edge1(
    const float* __restrict__ x, const int* __restrict__ idx1,
    const float* __restrict__ W1,
    const float* __restrict__ g1, const float* __restrict__ b1,
    const float* __restrict__ m1, const float* __restrict__ v1,
    float* __restrict__ x1, __bf16* __restrict__ x1h, __bf16* __restrict__ x1l,
    float* __restrict__ xx2)
{
  const int b = blockIdx.y;
  const int tid = threadIdx.x;
  const int w = tid >> 6, L = tid & 63;
  const int n = blockIdx.x*4 + w;
  const float* __restrict__ xr = x + (size_t)b*2*Np;
  const float* __restrict__ yr = xr + Np;

  const float px = xr[n], py = yr[n];
  const int o = L;
  const float4 w1v = reinterpret_cast<const float4*>(W1)[o];
  const float sc = g1[o] / sqrtf(v1[o] + EPSf);
  const float mo = m1[o], bo = b1[o];
  const float cterm = (w1v.z - w1v.x)*px + (w1v.w - w1v.y)*py;

  const int* ip = idx1 + ((size_t)b*Np + n)*Kn;
  float xm = NEGINF;
#pragma unroll
  for (int k = 0; k < Kn; ++k) {
    int j = ip[k];                 // wave-uniform -> scalar
    float xj = xr[j], yj = yr[j];
    float vv = w1v.x*xj + w1v.y*yj + cterm;
    float h = (vv - mo)*sc + bo;
    h = h >= 0.f ? h : SLOPE*h;
    xm = fmaxf(xm, h);
  }
  x1[(b*64 + o)*Np + n] = xm;
  __bf16 hb = (__bf16)xm;
  __bf16 lb = (__bf16)(xm - (float)hb);
  size_t tbase = ((size_t)b*Np + n)*64 + o;
  x1h[tbase] = hb;
  x1l[tbase] = lb;
  float s = xm*xm;
#pragma unroll
  for (int off = 1; off < 64; off <<= 1) s += __shfl_xor(s, off);
  if (L == 0) xx2[b*Np + n] = s;
}

// ---------------- K2: knn2 — 4-wave blocks, swapped-operand MFMA gram, exact top-20 -----
// grid (256 rowblocks, B), 256 thr. Block: 16 rows x 4096 cols; wave w takes tiles tt==w mod 4.
// D[n=L15 -> row][m=quad*4+r -> col]; lane owns one row. Key=(sortable(e)<<32)|~j,
// e = 2*dot - ||x_j||^2.
__global__ __launch_bounds__(256) void k2_knn2(
    const __bf16* __restrict__ xh, const __bf16* __restrict__ xl,
    const float* __restrict__ xx2, int* __restrict__ idx2)
{
  __shared__ ull smem[5120];   // 40 KB. phase1: sxx float[4096] @0 (2048 ull) + pbuf[10][256] @2048
                               // phase2: dump[4][64][20] @0 (5120 ull)
  float* sxx = (float*)smem;
  ull* pbuf = smem + 2048;

  const int b = blockIdx.y;
  const int n0 = blockIdx.x * 16;
  const int tid = threadIdx.x;
  const int w = tid >> 6, L = tid & 63;
  const int L15 = L & 15, quad = L >> 4;

  for (int j = tid*4; j < Np; j += 1024)
    *reinterpret_cast<float4*>(&sxx[j]) = *reinterpret_cast<const float4*>(&xx2[(size_t)b*Np + j]);

  // B operand: rows n0..n0+15 (each wave loads its own copy)
  const __bf16* Rh = xh + ((size_t)b*Np + n0)*64;
  const __bf16* Rl = xl + ((size_t)b*Np + n0)*64;
  bf16x8 rh0 = *reinterpret_cast<const bf16x8*>(Rh + L15*64 +  0 + quad*8);
  bf16x8 rh1 = *reinterpret_cast<const bf16x8*>(Rh + L15*64 + 32 + quad*8);
  bf16x8 rl0 = *reinterpret_cast<const bf16x8*>(Rl + L15*64 +  0 + quad*8);
  bf16x8 rl1 = *reinterpret_cast<const bf16x8*>(Rl + L15*64 + 32 + quad*8);

  const __bf16* Cbh = xh + (size_t)b*Np*64;
  const __bf16* Cbl = xl + (size_t)b*Np*64;

  ull kv[20];
#pragma unroll
  for (int s = 0; s < 20; ++s) kv[s] = 0ull;
  float fthresh = NEGINF;
  int cnt = 0;

  __syncthreads();   // sxx ready

  auto flush = [&]() {
    ull t0[10];
#pragma unroll
    for (int f = 0; f < 10; ++f) t0[f] = pbuf[f*256 + tid];
#pragma unroll 1
    for (int f = 0; f < 10; ++f) {
      if (__all(f >= cnt)) break;
      ull key = t0[f];
      if (f < cnt && key > kv[19]) {
        ull ck = key;
#pragma unroll
        for (int s = 0; s < 20; ++s) {
          bool sw = ck > kv[s];
          ull tv = kv[s];
          kv[s] = sw ? ck : kv[s];
          ck = sw ? tv : ck;
        }
      }
    }
    cnt = 0;
    // row threshold = max of kv[19] over the row's 4 quad-lanes (exact lower bound)
    ull t = kv[19];
    ull t2 = __shfl_xor(t, 16); t = t2 > t ? t2 : t;
    t2 = __shfl_xor(t, 32);     t = t2 > t ? t2 : t;
    if (t != 0ull) {
      u32 hk = (u32)(t >> 32);
      u32 u = (hk >> 31) ? (hk ^ 0x80000000u) : ~hk;
      fthresh = __uint_as_float(u);
    }
  };

  for (int t = 0; t < 16; ++t) {
    const int tt = w + t*4;
    const int colbase = tt * 64;
    const __bf16* ph = Cbh + (size_t)colbase*64;
    const __bf16* pl = Cbl + (size_t)colbase*64;
    bf16x8 AH[4][2], AL[4][2];
#pragma unroll
    for (int s = 0; s < 4; ++s) {
      AH[s][0] = *reinterpret_cast<const bf16x8*>(ph + (s*16 + L15)*64 +  0 + quad*8);
      AH[s][1] = *reinterpret_cast<const bf16x8*>(ph + (s*16 + L15)*64 + 32 + quad*8);
      AL[s][0] = *reinterpret_cast<const bf16x8*>(pl + (s*16 + L15)*64 +  0 + quad*8);
      AL[s][1] = *reinterpret_cast<const bf16x8*>(pl + (s*16 + L15)*64 + 32 + quad*8);
    }

    f32x4 acc[4];
#pragma unroll
    for (int s = 0; s < 4; ++s) {
      acc[s] = (f32x4){0.f, 0.f, 0.f, 0.f};
      acc[s] = __builtin_amdgcn_mfma_f32_16x16x32_bf16(AH[s][0], rh0, acc[s], 0, 0, 0);
      acc[s] = __builtin_amdgcn_mfma_f32_16x16x32_bf16(AH[s][1], rh1, acc[s], 0, 0, 0);
      acc[s] = __builtin_amdgcn_mfma_f32_16x16x32_bf16(AH[s][0], rl0, acc[s], 0, 0, 0);
      acc[s] = __builtin_amdgcn_mfma_f32_16x16x32_bf16(AH[s][1], rl1, acc[s], 0, 0, 0);
      acc[s] = __builtin_amdgcn_mfma_f32_16x16x32_bf16(AL[s][0], rh0, acc[s], 0, 0, 0);
      acc[s] = __builtin_amdgcn_mfma_f32_16x16x32_bf16(AL[s][1], rh1, acc[s], 0, 0, 0);
    }

#pragma unroll
    for (int s = 0; s < 4; ++s) {
      float4 xv = *reinterpret_cast<const float4*>(&sxx[colbase + s*16 + quad*4]);
      const float xvr[4] = {xv.x, xv.y, xv.z, xv.w};
#pragma unroll
      for (int r = 0; r < 4; ++r) {
        float e = 2.0f*acc[s][r] - xvr[r];
        if (e >= fthresh) {
          int j = colbase + s*16 + quad*4 + r;
          u32 u = __float_as_uint(e);
          u32 hk = u ^ ((u32)((int)u >> 31) | 0x80000000u);
          pbuf[cnt*256 + tid] = (((ull)hk) << 32) | (u32)~(u32)j;
          ++cnt;
        }
      }
      if (__any(cnt >= 6)) flush();   // cap 10: max cnt 5+4=9
    }
  }
  flush();

  __syncthreads();   // all waves done scanning: sxx/pbuf dead -> dump layout
#pragma unroll
  for (int k = 0; k < Kn; ++k) smem[((size_t)w*64 + L)*20 + k] = kv[k];
  __syncthreads();

  if (tid < 16) {
    const int r = tid;
    ull h[16]; int pc[16];
#pragma unroll
    for (int i = 0; i < 16; ++i) {
      h[i] = smem[((size_t)(i>>2)*64 + (i&3)*16 + r)*20];
      pc[i] = 0;
    }
    size_t obase = ((size_t)b*Np + n0 + r)*Kn;
    for (int k = 0; k < Kn; ++k) {
      ull best = h[0]; int sel = 0;
#pragma unroll
      for (int i = 1; i < 16; ++i) if (h[i] > best) { best = h[i]; sel = i; }
      idx2[obase + k] = (int)~(u32)best;
      int np_ = ++pc[sel];
      h[sel] = (np_ < 20) ? smem[((size_t)(sel>>2)*64 + (sel&3)*16 + r)*20 + np_] : 0ull;
    }
  }
}

// ---------------- K3: edgeconv2 (one wave per point, W2 rows in registers) ----------------
__global__ __launch_bounds__(256) void k3_edge2(
    const __bf16* __restrict__ xh, const __bf16* __restrict__ xl,
    const int* __restrict__ idx2,
    const float* __restrict__ W2,
    const float* __restrict__ g2, const float* __restrict__ b2,
    const float* __restrict__ m2, const float* __restrict__ v2,
    float* __restrict__ x2)
{
  __shared__ float scen[4][64];
  __shared__ float snbr[4][64];
  const int b = blockIdx.y;
  const int tid = threadIdx.x;
  const int w = tid >> 6, L = tid & 63;
  const int n = blockIdx.x*4 + w;

  float4 w2a[16], w2b[16];
#pragma unroll
  for (int q = 0; q < 16; ++q) {
    w2a[q] = reinterpret_cast<const float4*>(W2 + L*128)[q];
    w2b[q] = reinterpret_cast<const float4*>(W2 + L*128 + 64)[q];
  }
  const float sc2 = g2[L]/sqrtf(v2[L]+EPSf);
  const float m2o = m2[L], b2o = b2[L];

  float cen = (float)xh[((size_t)b*Np + n)*64 + L] + (float)xl[((size_t)b*Np + n)*64 + L];
  scen[w][L] = cen;
  __syncthreads();
  float u = 0.f, t2 = 0.f;
#pragma unroll
  for (int q = 0; q < 16; ++q) {
    float4 cv = *reinterpret_cast<const float4*>(&scen[w][q*4]);
    u  += w2a[q].x*cv.x + w2a[q].y*cv.y + w2a[q].z*cv.z + w2a[q].w*cv.w;
    t2 += w2b[q].x*cv.x + w2b[q].y*cv.y + w2b[q].z*cv.z + w2b[q].w*cv.w;
  }

  const int* ip = idx2 + ((size_t)b*Np + n)*Kn;
  float xm = NEGINF;
  int j0 = ip[0];
  float cur = (float)xh[((size_t)b*Np + j0)*64 + L] + (float)xl[((size_t)b*Np + j0)*64 + L];
  for (int k = 0; k < Kn; ++k) {
    float nxt = 0.f;
    if (k+1 < Kn) {
      int jn = ip[k+1];
      nxt = (float)xh[((size_t)b*Np + jn)*64 + L] + (float)xl[((size_t)b*Np + jn)*64 + L];
    }
    snbr[w][L] = cur;
    float a = 0.f;
#pragma unroll
    for (int q = 0; q < 16; ++q) {
      float4 nv = *reinterpret_cast<const float4*>(&snbr[w][q*4]);
      a += w2a[q].x*nv.x + w2a[q].y*nv.y + w2a[q].z*nv.z + w2a[q].w*nv.w;
    }
    float vv = a - u + t2;
    float hh = (vv - m2o)*sc2 + b2o;
    hh = hh >= 0.f ? hh : SLOPE*hh;
    xm = fmaxf(xm, hh);
    cur = nxt;
  }
  x2[(b*64 + L)*Np + n] = xm;
}

// ---------------- K4: conv5 + per-block max over n ----------------
__global__ __launch_bounds__(256) void k4_conv5max(
    const float* __restrict__ x1, const float* __restrict__ x2,
    const float* __restrict__ W5,
    const float* __restrict__ g5, const float* __restrict__ b5,
    const float* __restrict__ m5, const float* __restrict__ v5,
    float* __restrict__ partials)  // (B,128,64)
{
  const int b = blockIdx.y, nb = blockIdx.x;
  const int tid = threadIdx.x;
  const int p = tid & 63;
  const int g = __builtin_amdgcn_readfirstlane(tid >> 6);
  const int n = nb*64 + p;
  float xcr[128];
#pragma unroll
  for (int c = 0; c < 64; ++c) {
    xcr[c]    = x1[(b*64 + c)*Np + n];
    xcr[64+c] = x2[(b*64 + c)*Np + n];
  }
  for (int oi = 0; oi < 32; ++oi) {
    const int o = g*32 + oi;
    const float* wr = W5 + o*128;
    float dot = 0.f;
#pragma unroll
    for (int c = 0; c < 128; c += 4) {
      float4 wv = *reinterpret_cast<const float4*>(wr + c);
      dot += wv.x*xcr[c] + wv.y*xcr[c+1] + wv.z*xcr[c+2] + wv.w*xcr[c+3];
    }
    float hv = (dot - m5[o])*(g5[o]/sqrtf(v5[o]+EPSf)) + b5[o];
    hv = hv >= 0.f ? hv : SLOPE*hv;
#pragma unroll
    for (int off = 1; off < 64; off <<= 1) hv = fmaxf(hv, __shfl_xor(hv, off));
    if (p == 0) partials[(b*128 + o)*64 + nb] = hv;
  }
}

// ---------------- K5: reduce partial maxima -> gmax, then t6 = W6a * gmax ----------------
__global__ __launch_bounds__(256) void k5_reduce_t6(
    const float* __restrict__ partials, const float* __restrict__ W6,
    float* __restrict__ t6)  // (B,256)
{
  __shared__ float sg[128];
  const int b = blockIdx.x;
  const int tid = threadIdx.x;
  if (tid < 128) {
    float m = NEGINF;
    for (int w = 0; w < 64; ++w) m = fmaxf(m, partials[(b*128 + tid)*64 + w]);
    sg[tid] = m;
  }
  __syncthreads();
  float a = 0.f;
#pragma unroll
  for (int c = 0; c < 128; c += 4) {
    float4 wv = *reinterpret_cast<const float4*>(W6 + tid*256 + c);
    a += wv.x*sg[c] + wv.y*sg[c+1] + wv.z*sg[c+2] + wv.w*sg[c+3];
  }
  t6[b*256 + tid] = a;
}

// ---------------- K6: conv6 (W6b part + t6) + bn + lrelu + W9 dot ----------------
__global__ __launch_bounds__(256) void k6_conv6_out(
    const float* __restrict__ x1, const float* __restrict__ x2,
    const float* __restrict__ W6, const float* __restrict__ t6,
    const float* __restrict__ g6, const float* __restrict__ b6,
    const float* __restrict__ m6, const float* __restrict__ v6,
    const float* __restrict__ W9,
    float* __restrict__ out)
{
  __shared__ float red[4][64];
  const int b = blockIdx.y, nb = blockIdx.x;
  const int tid = threadIdx.x;
  const int p = tid & 63;
  const int g = __builtin_amdgcn_readfirstlane(tid >> 6);
  const int n = nb*64 + p;
  float xcr[128];
#pragma unroll
  for (int c = 0; c < 64; ++c) {
    xcr[c]    = x1[(b*64 + c)*Np + n];
    xcr[64+c] = x2[(b*64 + c)*Np + n];
  }
  float oacc = 0.f;
  for (int oi = 0; oi < 64; ++oi) {
    const int o = g*64 + oi;
    const float* wr = W6 + o*256 + 128;
    float dot = t6[b*256 + o];
#pragma unroll
    for (int c = 0; c < 128; c += 4) {
      float4 wv = *reinterpret_cast<const float4*>(wr + c);
      dot += wv.x*xcr[c] + wv.y*xcr[c+1] + wv.z*xcr[c+2] + wv.w*xcr[c+3];
    }
    float hv = (dot - m6[o])*(g6[o]/sqrtf(v6[o]+EPSf)) + b6[o];
    hv = hv >= 0.f ? hv : SLOPE*hv;
    oacc += W9[o]*hv;
  }
  red[g][p] = oacc;
  __syncthreads();
  if (tid < 64)
    out[b*Np + nb*64 + tid] = red[0][tid] + red[1][tid] + red[2][tid] + red[3][tid];
}

extern "C" void kernel_launch(void* const* d_in, const int* in_sizes, int n_in,
                              void* d_out, int out_size, void* d_ws, size_t ws_size,
                              hipStream_t stream) {
  const float* x  = (const float*)d_in[0];
  const float* W1 = (const float*)d_in[1];
  const float* g1 = (const float*)d_in[2];
  const float* b1 = (const float*)d_in[3];
  const float* m1 = (const float*)d_in[4];
  const float* v1 = (const float*)d_in[5];
  const float* W2 = (const float*)d_in[6];
  const float* g2 = (const float*)d_in[7];
  const float* b2 = (const float*)d_in[8];
  const float* m2 = (const float*)d_in[9];
  const float* v2 = (const float*)d_in[10];
  const float* W5 = (const float*)d_in[11];
  const float* g5 = (const float*)d_in[12];
  const float* b5 = (const float*)d_in[13];
  const float* m5 = (const float*)d_in[14];
  const float* v5 = (const float*)d_in[15];
  const float* W6 = (const float*)d_in[16];
  const float* g6 = (const float*)d_in[17];
  const float* b6 = (const float*)d_in[18];
  const float* m6 = (const float*)d_in[19];
  const float* v6 = (const float*)d_in[20];
  const float* W9 = (const float*)d_in[21];
  float* out = (float*)d_out;

  float* F = (float*)d_ws;
  float*  x1    = F;                         // 1048576
  float*  xx2   = F + 1048576;               // 16384
  __bf16* x1h   = (__bf16*)(F + 1064960);    // 524288 float-slots
  __bf16* x1l   = (__bf16*)(F + 1589248);    // 524288
  float*  x2    = F + 2113536;               // 1048576
  int*    idx1  = (int*)(F + 2113536);       // 327680 — aliases x2; dead before k3 writes x2
  int*    idx2  = (int*)(F + 3162112);       // 327680
  float*  t6    = F + 3489792;               // 1024
  float*  parts = F + 3490816;               // 32768

  k1a_knn1<<<dim3(64,4), 256, 0, stream>>>(x, idx1);
  k1c_edge1<<<dim3(1024,4), 256, 0, stream>>>(x, idx1, W1, g1, b1, m1, v1, x1, x1h, x1l, xx2);
  k2_knn2<<<dim3(256,4), 256, 0, stream>>>(x1h, x1l, xx2, idx2);
  k3_edge2<<<dim3(1024,4), 256, 0, stream>>>(x1h, x1l, idx2, W2, g2, b2, m2, v2, x2);
  k4_conv5max<<<dim3(64,4), 256, 0, stream>>>(x1, x2, W5, g5, b5, m5, v5, parts);
  k5_reduce_t6<<<4, 256, 0, stream>>>(parts, W6, t6);
  k6_conv6_out<<<dim3(64,4), 256, 0, stream>>>(x1, x2, W6, t6, g6, b6, m6, v6, W9, out);
}

// Round 7
// 738.038 us; speedup vs baseline: 1.3351x; 1.0246x over previous
//
#include <hip/hip_runtime.h>
#include <math.h>

#define NEGINF (-INFINITY)
constexpr int Np = 4096;
constexpr int Kn = 20;
constexpr float EPSf = 1e-5f;
constexpr float SLOPE = 0.2f;

typedef __bf16 bf16x8 __attribute__((ext_vector_type(8)));
typedef float f32x4 __attribute__((ext_vector_type(4)));
typedef unsigned long long ull;
typedef unsigned int u32;

// ---------------- K1: knn1 + edgeconv1 fused ----------------
// grid (64, B), 256 thr, __launch_bounds__(256,2) so kv[20] stays in arch VGPRs.
// Phase 1: wave w scans slice [w*1024,(w+1)*1024) for the block's 64 points
//          (lane L = point n0+L). Key = (~bits(d2)<<32) | ~j.
// Phase 2: 4-way merge -> merged top-20 idx in LDS.
// Phase 3: edgeconv1, wave handles 16 points, lane = channel.
__global__ __launch_bounds__(256, 2) void k1_knn1_edge1(
    const float* __restrict__ x, const float* __restrict__ W1,
    const float* __restrict__ g1, const float* __restrict__ b1,
    const float* __restrict__ m1, const float* __restrict__ v1,
    float* __restrict__ x1, __bf16* __restrict__ x1h, __bf16* __restrict__ x1l,
    float* __restrict__ xx2)
{
  __shared__ ull smem[6144];   // 48 KB: pbuf[24][256] ph1; dump[4][64][20]+midx ph2/3

  const int b = blockIdx.y;
  const int n0 = blockIdx.x * 64;
  const int tid = threadIdx.x;
  const int w = tid >> 6, L = tid & 63;
  const float* __restrict__ xr = x + (size_t)b*2*Np;
  const float* __restrict__ yr = xr + Np;

  const int n = n0 + L;
  const float px = xr[n], py = yr[n];

  ull kv[20];
#pragma unroll
  for (int s = 0; s < 20; ++s) kv[s] = 0ull;
  u32 u_cut = 0xFFFFFFFFu;
  int cnt = 0;

  auto flushK = [&]() {
#pragma unroll 1
    for (int f0 = 0; f0 < 24; f0 += 8) {
      if (__all(f0 >= cnt)) break;
      ull t0[8];
#pragma unroll
      for (int u = 0; u < 8; ++u) t0[u] = smem[(f0+u)*256 + tid];
#pragma unroll
      for (int u = 0; u < 8; ++u) {
        int f = f0 + u;
        ull key = t0[u];
        if (f < cnt && key > kv[19]) {
          ull ck = key;
#pragma unroll
          for (int s = 0; s < 20; ++s) {
            bool sw = ck > kv[s];
            ull tv = kv[s];
            kv[s] = sw ? ck : kv[s];
            ck = sw ? tv : ck;
          }
        }
      }
    }
    cnt = 0;
    u_cut = ~(u32)(kv[19] >> 32);
  };

  const int base = w * 1024;
  for (int j0 = base; j0 < base + 1024; j0 += 16) {
#pragma unroll
    for (int c = 0; c < 4; ++c) {
      float4 xv = *reinterpret_cast<const float4*>(xr + j0 + c*4);  // uniform -> s_load
      float4 yv = *reinterpret_cast<const float4*>(yr + j0 + c*4);
      const float xs[4] = {xv.x, xv.y, xv.z, xv.w};
      const float ys[4] = {yv.x, yv.y, yv.z, yv.w};
#pragma unroll
      for (int r = 0; r < 4; ++r) {
        float dx = xs[r] - px, dy = ys[r] - py;
        float s = dx*dx + dy*dy;
        u32 ub = __float_as_uint(s);
        if (ub <= u_cut) {
          int j = j0 + c*4 + r;
          smem[cnt*256 + tid] = (((ull)~ub) << 32) | (u32)~(u32)j;
          ++cnt;
        }
      }
    }
    if (__any(cnt >= 8)) flushK();
  }
  flushK();

  __syncthreads();             // pbuf dead; switch to dump layout
#pragma unroll
  for (int k = 0; k < Kn; ++k) smem[((size_t)w*64 + L)*20 + k] = kv[k];
  __syncthreads();

  u32* midx = (u32*)(smem + 5120);   // 64 x 20 merged indices
  if (tid < 64) {
    const int p = tid;
    ull h[4]; int pc[4];
#pragma unroll
    for (int q = 0; q < 4; ++q) { h[q] = smem[((size_t)q*64 + p)*20]; pc[q] = 0; }
    for (int k = 0; k < Kn; ++k) {
      ull best = h[0]; int sel = 0;
      if (h[1] > best) { best = h[1]; sel = 1; }
      if (h[2] > best) { best = h[2]; sel = 2; }
      if (h[3] > best) { best = h[3]; sel = 3; }
      midx[p*20 + k] = (u32)~(u32)best;
      int np_ = ++pc[sel];
      h[sel] = (np_ < 20) ? smem[((size_t)sel*64 + p)*20 + np_] : 0ull;
    }
  }
  __syncthreads();

  // phase 3: edgeconv1 — wave w handles points w*16 .. w*16+15, lane = channel o
  const int o = L;
  const float4 w1v = reinterpret_cast<const float4*>(W1)[o];
  const float sc = g1[o] / sqrtf(v1[o] + EPSf);
  const float mo = m1[o], bo = b1[o];

  for (int pi = 0; pi < 16; ++pi) {
    const int p = w*16 + pi;
    const int np = n0 + p;
    const float cx0 = xr[np], cx1 = yr[np];          // uniform
    const float cterm = (w1v.z - w1v.x)*cx0 + (w1v.w - w1v.y)*cx1;
    float xm = NEGINF;
#pragma unroll
    for (int k = 0; k < Kn; ++k) {
      int j = __builtin_amdgcn_readfirstlane(midx[p*20 + k]);
      float xj = xr[j], yj = yr[j];                  // s_loads
      float vv = w1v.x*xj + w1v.y*yj + cterm;
      float h = (vv - mo)*sc + bo;
      h = h >= 0.f ? h : SLOPE*h;
      xm = fmaxf(xm, h);
    }
    x1[(b*64 + o)*Np + np] = xm;
    __bf16 hb = (__bf16)xm;
    __bf16 lb = (__bf16)(xm - (float)hb);
    size_t tbase = ((size_t)b*Np + np)*64 + o;
    x1h[tbase] = hb;
    x1l[tbase] = lb;
    float s = xm*xm;
#pragma unroll
    for (int off = 1; off < 64; off <<= 1) s += __shfl_xor(s, off);
    if (L == 0) xx2[b*Np + np] = s;
  }
}

// ---------------- K2: knn2 — 4-wave blocks, swapped-operand MFMA gram, exact top-20 -----
// grid (256 rowblocks, B), 256 thr. Block: 16 rows x 4096 cols; wave w takes tiles tt==w mod 4.
// D[n=L15 -> row][m=quad*4+r -> col]; lane owns one row. Key=(sortable(e)<<32)|~j,
// e = 2*dot - ||x_j||^2.
__global__ __launch_bounds__(256, 2) void k2_knn2(
    const __bf16* __restrict__ xh, const __bf16* __restrict__ xl,
    const float* __restrict__ xx2, int* __restrict__ idx2)
{
  __shared__ ull smem[5120];   // 40 KB. ph1: sxx float[4096] @0 + pbuf[10][256] @2048
                               // ph2: dump[4][64][20] @0
  float* sxx = (float*)smem;
  ull* pbuf = smem + 2048;

  const int b = blockIdx.y;
  const int n0 = blockIdx.x * 16;
  const int tid = threadIdx.x;
  const int w = tid >> 6, L = tid & 63;
  const int L15 = L & 15, quad = L >> 4;

  for (int j = tid*4; j < Np; j += 1024)
    *reinterpret_cast<float4*>(&sxx[j]) = *reinterpret_cast<const float4*>(&xx2[(size_t)b*Np + j]);

  // B operand: rows n0..n0+15
  const __bf16* Rh = xh + ((size_t)b*Np + n0)*64;
  const __bf16* Rl = xl + ((size_t)b*Np + n0)*64;
  bf16x8 rh0 = *reinterpret_cast<const bf16x8*>(Rh + L15*64 +  0 + quad*8);
  bf16x8 rh1 = *reinterpret_cast<const bf16x8*>(Rh + L15*64 + 32 + quad*8);
  bf16x8 rl0 = *reinterpret_cast<const bf16x8*>(Rl + L15*64 +  0 + quad*8);
  bf16x8 rl1 = *reinterpret_cast<const bf16x8*>(Rl + L15*64 + 32 + quad*8);

  const __bf16* Cbh = xh + (size_t)b*Np*64;
  const __bf16* Cbl = xl + (size_t)b*Np*64;

  ull kv[20];
#pragma unroll
  for (int s = 0; s < 20; ++s) kv[s] = 0ull;
  float fthresh = NEGINF;
  int cnt = 0;

  __syncthreads();   // sxx ready

  auto flush = [&]() {
    ull t0[10];
#pragma unroll
    for (int f = 0; f < 10; ++f) t0[f] = pbuf[f*256 + tid];
#pragma unroll 1
    for (int f = 0; f < 10; ++f) {
      if (__all(f >= cnt)) break;
      ull key = t0[f];
      if (f < cnt && key > kv[19]) {
        ull ck = key;
#pragma unroll
        for (int s = 0; s < 20; ++s) {
          bool sw = ck > kv[s];
          ull tv = kv[s];
          kv[s] = sw ? ck : kv[s];
          ck = sw ? tv : ck;
        }
      }
    }
    cnt = 0;
    ull t = kv[19];
    ull t2 = __shfl_xor(t, 16); t = t2 > t ? t2 : t;
    t2 = __shfl_xor(t, 32);     t = t2 > t ? t2 : t;
    if (t != 0ull) {
      u32 hk = (u32)(t >> 32);
      u32 u = (hk >> 31) ? (hk ^ 0x80000000u) : ~hk;
      fthresh = __uint_as_float(u);
    }
  };

  for (int t = 0; t < 16; ++t) {
    const int tt = w + t*4;
    const int colbase = tt * 64;
    const __bf16* ph = Cbh + (size_t)colbase*64;
    const __bf16* pl = Cbl + (size_t)colbase*64;
    bf16x8 AH[4][2], AL[4][2];
#pragma unroll
    for (int s = 0; s < 4; ++s) {
      AH[s][0] = *reinterpret_cast<const bf16x8*>(ph + (s*16 + L15)*64 +  0 + quad*8);
      AH[s][1] = *reinterpret_cast<const bf16x8*>(ph + (s*16 + L15)*64 + 32 + quad*8);
      AL[s][0] = *reinterpret_cast<const bf16x8*>(pl + (s*16 + L15)*64 +  0 + quad*8);
      AL[s][1] = *reinterpret_cast<const bf16x8*>(pl + (s*16 + L15)*64 + 32 + quad*8);
    }

    f32x4 acc[4];
#pragma unroll
    for (int s = 0; s < 4; ++s) {
      acc[s] = (f32x4){0.f, 0.f, 0.f, 0.f};
      acc[s] = __builtin_amdgcn_mfma_f32_16x16x32_bf16(AH[s][0], rh0, acc[s], 0, 0, 0);
      acc[s] = __builtin_amdgcn_mfma_f32_16x16x32_bf16(AH[s][1], rh1, acc[s], 0, 0, 0);
      acc[s] = __builtin_amdgcn_mfma_f32_16x16x32_bf16(AH[s][0], rl0, acc[s], 0, 0, 0);
      acc[s] = __builtin_amdgcn_mfma_f32_16x16x32_bf16(AH[s][1], rl1, acc[s], 0, 0, 0);
      acc[s] = __builtin_amdgcn_mfma_f32_16x16x32_bf16(AL[s][0], rh0, acc[s], 0, 0, 0);
      acc[s] = __builtin_amdgcn_mfma_f32_16x16x32_bf16(AL[s][1], rh1, acc[s], 0, 0, 0);
    }

#pragma unroll
    for (int s = 0; s < 4; ++s) {
      float4 xv = *reinterpret_cast<const float4*>(&sxx[colbase + s*16 + quad*4]);
      const float xvr[4] = {xv.x, xv.y, xv.z, xv.w};
#pragma unroll
      for (int r = 0; r < 4; ++r) {
        float e = 2.0f*acc[s][r] - xvr[r];
        if (e >= fthresh) {
          int j = colbase + s*16 + quad*4 + r;
          u32 u = __float_as_uint(e);
          u32 hk = u ^ ((u32)((int)u >> 31) | 0x80000000u);
          pbuf[cnt*256 + tid] = (((ull)hk) << 32) | (u32)~(u32)j;
          ++cnt;
        }
      }
      if (__any(cnt >= 6)) flush();   // cap 10: max cnt 5+4=9
    }
  }
  flush();

  __syncthreads();   // sxx/pbuf dead -> dump layout
#pragma unroll
  for (int k = 0; k < Kn; ++k) smem[((size_t)w*64 + L)*20 + k] = kv[k];
  __syncthreads();

  if (tid < 16) {
    const int r = tid;
    ull h[16]; int pc[16];
#pragma unroll
    for (int i = 0; i < 16; ++i) {
      h[i] = smem[((size_t)(i>>2)*64 + (i&3)*16 + r)*20];
      pc[i] = 0;
    }
    size_t obase = ((size_t)b*Np + n0 + r)*Kn;
    for (int k = 0; k < Kn; ++k) {
      ull best = h[0]; int sel = 0;
#pragma unroll
      for (int i = 1; i < 16; ++i) if (h[i] > best) { best = h[i]; sel = i; }
      idx2[obase + k] = (int)~(u32)best;
      int np_ = ++pc[sel];
      h[sel] = (np_ < 20) ? smem[((size_t)(sel>>2)*64 + (sel&3)*16 + r)*20 + np_] : 0ull;
    }
  }
}

// ---------------- K3: edgeconv2 (one wave per point, W2 rows in registers) ----------------
__global__ __launch_bounds__(256, 2) void k3_edge2(
    const __bf16* __restrict__ xh, const __bf16* __restrict__ xl,
    const int* __restrict__ idx2,
    const float* __restrict__ W2,
    const float* __restrict__ g2, const float* __restrict__ b2,
    const float* __restrict__ m2, const float* __restrict__ v2,
    float* __restrict__ x2)
{
  __shared__ float scen[4][64];
  __shared__ float snbr[4][64];
  const int b = blockIdx.y;
  const int tid = threadIdx.x;
  const int w = tid >> 6, L = tid & 63;
  const int n = blockIdx.x*4 + w;

  float4 w2a[16], w2b[16];
#pragma unroll
  for (int q = 0; q < 16; ++q) {
    w2a[q] = reinterpret_cast<const float4*>(W2 + L*128)[q];
    w2b[q] = reinterpret_cast<const float4*>(W2 + L*128 + 64)[q];
  }
  const float sc2 = g2[L]/sqrtf(v2[L]+EPSf);
  const float m2o = m2[L], b2o = b2[L];

  float cen = (float)xh[((size_t)b*Np + n)*64 + L] + (float)xl[((size_t)b*Np + n)*64 + L];
  scen[w][L] = cen;
  __syncthreads();
  float u = 0.f, t2 = 0.f;
#pragma unroll
  for (int q = 0; q < 16; ++q) {
    float4 cv = *reinterpret_cast<const float4*>(&scen[w][q*4]);
    u  += w2a[q].x*cv.x + w2a[q].y*cv.y + w2a[q].z*cv.z + w2a[q].w*cv.w;
    t2 += w2b[q].x*cv.x + w2b[q].y*cv.y + w2b[q].z*cv.z + w2b[q].w*cv.w;
  }

  const int* ip = idx2 + ((size_t)b*Np + n)*Kn;
  float xm = NEGINF;
  int j0 = ip[0];
  float cur = (float)xh[((size_t)b*Np + j0)*64 + L] + (float)xl[((size_t)b*Np + j0)*64 + L];
  for (int k = 0; k < Kn; ++k) {
    float nxt = 0.f;
    if (k+1 < Kn) {
      int jn = ip[k+1];
      nxt = (float)xh[((size_t)b*Np + jn)*64 + L] + (float)xl[((size_t)b*Np + jn)*64 + L];
    }
    snbr[w][L] = cur;
    float a = 0.f;
#pragma unroll
    for (int q = 0; q < 16; ++q) {
      float4 nv = *reinterpret_cast<const float4*>(&snbr[w][q*4]);
      a += w2a[q].x*nv.x + w2a[q].y*nv.y + w2a[q].z*nv.z + w2a[q].w*nv.w;
    }
    float vv = a - u + t2;
    float hh = (vv - m2o)*sc2 + b2o;
    hh = hh >= 0.f ? hh : SLOPE*hh;
    xm = fmaxf(xm, hh);
    cur = nxt;
  }
  x2[(b*64 + L)*Np + n] = xm;
}

// ---------------- K4: conv5 + per-block max over n ----------------
__global__ __launch_bounds__(256) void k4_conv5max(
    const float* __restrict__ x1, const float* __restrict__ x2,
    const float* __restrict__ W5,
    const float* __restrict__ g5, const float* __restrict__ b5,
    const float* __restrict__ m5, const float* __restrict__ v5,
    float* __restrict__ partials)  // (B,128,64)
{
  const int b = blockIdx.y, nb = blockIdx.x;
  const int tid = threadIdx.x;
  const int p = tid & 63;
  const int g = __builtin_amdgcn_readfirstlane(tid >> 6);
  const int n = nb*64 + p;
  float xcr[128];
#pragma unroll
  for (int c = 0; c < 64; ++c) {
    xcr[c]    = x1[(b*64 + c)*Np + n];
    xcr[64+c] = x2[(b*64 + c)*Np + n];
  }
  for (int oi = 0; oi < 32; ++oi) {
    const int o = g*32 + oi;
    const float* wr = W5 + o*128;
    float dot = 0.f;
#pragma unroll
    for (int c = 0; c < 128; c += 4) {
      float4 wv = *reinterpret_cast<const float4*>(wr + c);
      dot += wv.x*xcr[c] + wv.y*xcr[c+1] + wv.z*xcr[c+2] + wv.w*xcr[c+3];
    }
    float hv = (dot - m5[o])*(g5[o]/sqrtf(v5[o]+EPSf)) + b5[o];
    hv = hv >= 0.f ? hv : SLOPE*hv;
#pragma unroll
    for (int off = 1; off < 64; off <<= 1) hv = fmaxf(hv, __shfl_xor(hv, off));
    if (p == 0) partials[(b*128 + o)*64 + nb] = hv;
  }
}

// ---------------- K5: reduce partial maxima -> gmax, then t6 = W6a * gmax ----------------
__global__ __launch_bounds__(256) void k5_reduce_t6(
    const float* __restrict__ partials, const float* __restrict__ W6,
    float* __restrict__ t6)  // (B,256)
{
  __shared__ float sg[128];
  const int b = blockIdx.x;
  const int tid = threadIdx.x;
  if (tid < 128) {
    float m = NEGINF;
    for (int w = 0; w < 64; ++w) m = fmaxf(m, partials[(b*128 + tid)*64 + w]);
    sg[tid] = m;
  }
  __syncthreads();
  float a = 0.f;
#pragma unroll
  for (int c = 0; c < 128; c += 4) {
    float4 wv = *reinterpret_cast<const float4*>(W6 + tid*256 + c);
    a += wv.x*sg[c] + wv.y*sg[c+1] + wv.z*sg[c+2] + wv.w*sg[c+3];
  }
  t6[b*256 + tid] = a;
}

// ---------------- K6: conv6 (W6b part + t6) + bn + lrelu + W9 dot ----------------
__global__ __launch_bounds__(256) void k6_conv6_out(
    const float* __restrict__ x1, const float* __restrict__ x2,
    const float* __restrict__ W6, const float* __restrict__ t6,
    const float* __restrict__ g6, const float* __restrict__ b6,
    const float* __restrict__ m6, const float* __restrict__ v6,
    const float* __restrict__ W9,
    float* __restrict__ out)
{
  __shared__ float red[4][64];
  const int b = blockIdx.y, nb = blockIdx.x;
  const int tid = threadIdx.x;
  const int p = tid & 63;
  const int g = __builtin_amdgcn_readfirstlane(tid >> 6);
  const int n = nb*64 + p;
  float xcr[128];
#pragma unroll
  for (int c = 0; c < 64; ++c) {
    xcr[c]    = x1[(b*64 + c)*Np + n];
    xcr[64+c] = x2[(b*64 + c)*Np + n];
  }
  float oacc = 0.f;
  for (int oi = 0; oi < 64; ++oi) {
    const int o = g*64 + oi;
    const float* wr = W6 + o*256 + 128;
    float dot = t6[b*256 + o];
#pragma unroll
    for (int c = 0; c < 128; c += 4) {
      float4 wv = *reinterpret_cast<const float4*>(wr + c);
      dot += wv.x*xcr[c] + wv.y*xcr[c+1] + wv.z*xcr[c+2] + wv.w*xcr[c+3];
    }
    float hv = (dot - m6[o])*(g6[o]/sqrtf(v6[o]+EPSf)) + b6[o];
    hv = hv >= 0.f ? hv : SLOPE*hv;
    oacc += W9[o]*hv;
  }
  red[g][p] = oacc;
  __syncthreads();
  if (tid < 64)
    out[b*Np + nb*64 + tid] = red[0][tid] + red[1][tid] + red[2][tid] + red[3][tid];
}

extern "C" void kernel_launch(void* const* d_in, const int* in_sizes, int n_in,
                              void* d_out, int out_size, void* d_ws, size_t ws_size,
                              hipStream_t stream) {
  const float* x  = (const float*)d_in[0];
  const float* W1 = (const float*)d_in[1];
  const float* g1 = (const float*)d_in[2];
  const float* b1 = (const float*)d_in[3];
  const float* m1 = (const float*)d_in[4];
  const float* v1 = (const float*)d_in[5];
  const float* W2 = (const float*)d_in[6];
  const float* g2 = (const float*)d_in[7];
  const float* b2 = (const float*)d_in[8];
  const float* m2 = (const float*)d_in[9];
  const float* v2 = (const float*)d_in[10];
  const float* W5 = (const float*)d_in[11];
  const float* g5 = (const float*)d_in[12];
  const float* b5 = (const float*)d_in[13];
  const float* m5 = (const float*)d_in[14];
  const float* v5 = (const float*)d_in[15];
  const float* W6 = (const float*)d_in[16];
  const float* g6 = (const float*)d_in[17];
  const float* b6 = (const float*)d_in[18];
  const float* m6 = (const float*)d_in[19];
  const float* v6 = (const float*)d_in[20];
  const float* W9 = (const float*)d_in[21];
  float* out = (float*)d_out;

  float* F = (float*)d_ws;
  float*  x1    = F;                         // 1048576
  float*  xx2   = F + 1048576;               // 16384
  __bf16* x1h   = (__bf16*)(F + 1064960);    // 524288 float-slots
  __bf16* x1l   = (__bf16*)(F + 1589248);    // 524288
  float*  x2    = F + 2113536;               // 1048576
  int*    idx2  = (int*)(F + 3162112);       // 327680
  float*  t6    = F + 3489792;               // 1024
  float*  parts = F + 3490816;               // 32768

  k1_knn1_edge1<<<dim3(64,4), 256, 0, stream>>>(x, W1, g1, b1, m1, v1, x1, x1h, x1l, xx2);
  k2_knn2<<<dim3(256,4), 256, 0, stream>>>(x1h, x1l, xx2, idx2);
  k3_edge2<<<dim3(1024,4), 256, 0, stream>>>(x1h, x1l, idx2, W2, g2, b2, m2, v2, x2);
  k4_conv5max<<<dim3(64,4), 256, 0, stream>>>(x1, x2, W5, g5, b5, m5, v5, parts);
  k5_reduce_t6<<<4, 256, 0, stream>>>(parts, W6, t6);
  k6_conv6_out<<<dim3(64,4), 256, 0, stream>>>(x1, x2, W6, t6, g6, b6, m6, v6, W9, out);
}